// Round 6
// baseline (3311.453 us; speedup 1.0000x reference)
//
#include <hip/hip_runtime.h>
#include <math.h>

#define PI_F 3.14159265358979323846f

static constexpr int L_ = 512, D_ = 768, H_ = 12, DH_ = 64;
static constexpr int BL_ = 2048;            // B*L
static constexpr int BLD_ = BL_ * D_;       // 1572864
static constexpr int BH_ = 48;              // B*H

// ---------------- diagnostic sentinel ----------------
__global__ void sentinel_kernel(float* out, float code, float aux) {
  out[0] = code;
  out[1] = aux;
}

// ---------------- naive LayerNorm over D=768: 1 block/row, 64 thr ----------------
__global__ __launch_bounds__(64) void ln_naive(const float* __restrict__ x,
                                               const float* __restrict__ g,
                                               const float* __restrict__ b,
                                               float* __restrict__ xn) {
  int row = blockIdx.x, tid = threadIdx.x;
  __shared__ float sh[64];
  __shared__ float st[2];
  const float* xr = x + (size_t)row * D_;
  float s = 0.f, s2 = 0.f;
  for (int j = 0; j < 12; ++j) { float v = xr[tid + j * 64]; s += v; s2 += v * v; }
  sh[tid] = s;
  __syncthreads();
  if (tid == 0) { float a = 0.f; for (int i = 0; i < 64; ++i) a += sh[i]; st[0] = a / 768.f; }
  __syncthreads();
  sh[tid] = s2;
  __syncthreads();
  if (tid == 0) { float a = 0.f; for (int i = 0; i < 64; ++i) a += sh[i]; st[1] = a / 768.f; }
  __syncthreads();
  float mu = st[0];
  float var = st[1] - mu * mu;
  float rs = rsqrtf(var + 1e-5f);
  for (int j = 0; j < 12; ++j) {
    int c = tid + j * 64;
    xn[(size_t)row * D_ + c] = (xr[c] - mu) * rs * g[c] + b[c];
  }
}

// ---------------- naive GEMM: one thread per output element ----------------
template <int MODE>
__global__ __launch_bounds__(256) void gemm_naive(const float* __restrict__ A,
                                                  const float* __restrict__ Bm,
                                                  const float* __restrict__ bias,
                                                  float* __restrict__ O0,
                                                  float* __restrict__ O1,
                                                  float* __restrict__ O2,
                                                  int M, int N, int K) {
  int idx = blockIdx.x * 256 + threadIdx.x;
  if (idx >= M * N) return;
  int m = idx / N, n = idx - m * N;
  float acc = 0.f;
  const float* Ar = A + (size_t)m * K;
  for (int k = 0; k < K; ++k) acc += Ar[k] * Bm[(size_t)k * N + n];
  if (MODE == 0) {
    acc += bias[n];
    int sec = n / 768, c = n - sec * 768;
    float r = (sec < 2) ? ((acc > 0.f) ? acc + 1.f : expf(acc)) : acc;
    float* O = (sec == 0) ? O0 : ((sec == 1) ? O1 : O2);
    O[(size_t)m * 768 + c] = r;
  } else if (MODE == 1) {
    O0[(size_t)m * N + n] = acc / (1.f + expf(-acc));
  } else {
    O0[(size_t)m * N + n] = acc + bias[n];
  }
}

// ---------------- naive params: one thread per (token, head) ----------------
// Outputs gp = 1+gate and ce = ema SEPARATELY (mirrors np multiply order).
__global__ __launch_bounds__(256) void params_naive(const float* __restrict__ h1,
                                                    const float* __restrict__ Wb2,
                                                    const float* __restrict__ temp_p,
                                                    float* __restrict__ gate_out,
                                                    float* __restrict__ gp,
                                                    float* __restrict__ ce,
                                                    float* __restrict__ ld) {
  int idx = blockIdx.x * 256 + threadIdx.x;
  if (idx >= BL_ * H_) return;
  int t = idx / H_, h = idx - t * H_;
  float p[5];
  for (int j = 0; j < 5; ++j) {
    float a = 0.f;
    for (int k = 0; k < 128; ++k) a += h1[(size_t)t * 128 + k] * Wb2[k * 60 + h * 5 + j];
    p[j] = a;
  }
  float sa = 1.f / (1.f + expf(-p[0]));
  float sp = tanhf(p[1]) * PI_F;
  float ca = 1.f / (1.f + expf(-p[2]));
  float cp = tanhf(p[3]) * PI_F;
  float dec = 0.5f + 0.49f / (1.f + expf(-p[4]));
  float tmp = fminf(fmaxf(temp_p[0], 0.1f), 2.0f);
  float inter = tanhf(sa * ca * cosf(sp - cp)) * tmp;
  float gate = 1.f / (1.f + expf(-inter));
  gate_out[t * H_ + h] = gate;
  int b = t >> 9, l = t & 511;
  int bhl = (b * H_ + h) * L_ + l;
  gp[bhl] = 1.0f + gate;
  ce[bhl] = 1.0f - dec;
  ld[bhl] = logf(dec + 1e-8f);
}

// ---------------- naive cumulative log-decay: one thread per (b,h) ----------------
__global__ __launch_bounds__(64) void cld_naive(const float* __restrict__ ld,
                                                float* __restrict__ cld) {
  int bh = blockIdx.x * 64 + threadIdx.x;
  if (bh >= BH_) return;
  float run = 0.f;
  for (int l = 0; l < L_; ++l) {
    run += ld[(size_t)bh * L_ + l];
    cld[(size_t)bh * L_ + l] = fmaxf(run, -85.f);
  }
}

// ---------------- reference-mirroring recurrence (scaled-space fp32 cumsums) ----
// Mirrors np verbatim: CS[d][e] = cumsum(((k_d*v_e)*gp)*(ema*e^{-cld})),
// kv_states = CS*e^{cld}; cz = cumsum(k*(ema*e^{-cld})), z = cz*e^{cld}.
// The fp32 overflow of cz -> inf -> den=inf -> out=0 is thereby reproduced
// EXACTLY (IEEE: finite/inf = 0; LN(0-vector) = mem_b).
__global__ __launch_bounds__(64) void seq_ref(const float* __restrict__ qf,
                                              const float* __restrict__ kf,
                                              const float* __restrict__ vf,
                                              const float* __restrict__ gp,
                                              const float* __restrict__ ce,
                                              const float* __restrict__ cld,
                                              const float* __restrict__ mg,
                                              const float* __restrict__ mb,
                                              float* __restrict__ attn) {
  int bh = blockIdx.x;
  int b = bh / H_, h = bh - b * H_;
  int e = threadIdx.x;
  float CS[64];
#pragma unroll
  for (int d = 0; d < 64; ++d) CS[d] = 0.f;
  float cz = 0.f;
  __shared__ float ks[64], qs[64], sh[64];
  __shared__ float st[3];
  float gm = mg[e], gb = mb[e];
  for (int t = 0; t < L_; ++t) {
    int idx = bh * L_ + t;
    float c = cld[idx];
    float invdf = expf(-c);
    float df = expf(c);
    float gpt = gp[idx], cet = ce[idx];
    float s = cet * invdf;                 // np: (ema * inv_df)
    size_t rb = (size_t)(b * L_ + t) * D_ + h * DH_ + e;
    float kv = kf[rb], qv = qf[rb], ve = vf[rb];
    ks[e] = kv; qs[e] = qv;
    __syncthreads();
    float num = 0.f;
#pragma unroll
    for (int d = 0; d < 64; ++d) {
      float t1 = ks[d] * ve;               // einsum kf,vf
      float t2 = t1 * gpt;                 // * (1+gate)
      float t3 = t2 * s;                   // * (ema*inv_df)
      CS[d] = CS[d] + t3;                  // cumsum (same add order as np)
      float kvst = CS[d] * df;             // kv_states
      num += qs[d] * kvst;                 // einsum qf,kv_states
    }
    cz = cz + kv * s;                      // z cumsum (d=e); overflows to inf like np
    float zst = cz * df;                   // z_states[e] (inf once cz=inf)
    sh[e] = qv * zst;
    __syncthreads();
    if (e == 0) {
      float dsum = 0.f;
      for (int i = 0; i < 64; ++i) dsum += sh[i];
      st[0] = dsum + 1e-6f;                // den (may be +inf)
    }
    __syncthreads();
    float o = num / st[0];                 // finite/inf = 0 reproduces ref collapse
    sh[e] = o;
    __syncthreads();
    if (e == 0) {
      float s1 = 0.f, s2 = 0.f;
      for (int i = 0; i < 64; ++i) { s1 += sh[i]; s2 += sh[i] * sh[i]; }
      st[1] = s1 * (1.f / 64.f);
      st[2] = s2 * (1.f / 64.f);
    }
    __syncthreads();
    float mu = st[1];
    float var = st[2] - mu * mu;
    float rs = rsqrtf(var + 1e-5f);
    attn[rb] = (o - mu) * rs * gm + gb;
    __syncthreads();
  }
}

extern "C" void kernel_launch(void* const* d_in, const int* in_sizes, int n_in,
                              void* d_out, int out_size, void* d_ws, size_t ws_size,
                              hipStream_t stream) {
  const float* x     = (const float*)d_in[0];
  const float* Wqkv  = (const float*)d_in[1];
  const float* bqkv  = (const float*)d_in[2];
  const float* Wb1   = (const float*)d_in[3];
  const float* Wb2   = (const float*)d_in[4];
  const float* temp  = (const float*)d_in[5];
  const float* Wproj = (const float*)d_in[6];
  const float* bproj = (const float*)d_in[7];
  const float* lng   = (const float*)d_in[8];
  const float* lnb   = (const float*)d_in[9];
  const float* memg  = (const float*)d_in[10];
  const float* memb  = (const float*)d_in[11];
  float* out0 = (float*)d_out;     // fp32 output (established r0-r5)
  float* gate = out0 + BLD_;

  static const int expect[12] = {1572864, 1769472, 2304, 98304, 7680, 1,
                                 589824, 768, 768, 768, 64, 64};
  int bad = (n_in == 12) ? -1 : 99;
  if (bad < 0) for (int i = 0; i < 12; ++i) if (in_sizes[i] != expect[i]) { bad = i; break; }
  size_t need = (size_t)(4 * BLD_ + 262144 + 4 * 24576) * sizeof(float);
  if (bad >= 0) { sentinel_kernel<<<1, 1, 0, stream>>>(out0, 3.0e6f, (float)bad); return; }
  if (ws_size < need) { sentinel_kernel<<<1, 1, 0, stream>>>(out0, 1.0e6f, (float)(ws_size >> 20)); return; }

  float* ws   = (float*)d_ws;
  float* xn   = ws;                  // BLD_; dead after qkv GEMM, reused as attn
  float* qfb  = xn + BLD_;
  float* kfb  = qfb + BLD_;
  float* vfb  = kfb + BLD_;
  float* h1   = vfb + BLD_;          // 2048*128
  float* gpb  = h1 + 262144;         // 1+gate, (B,H,L)
  float* ceb  = gpb + 24576;         // ema
  float* ldb  = ceb + 24576;
  float* cldb = ldb + 24576;
  float* attn = xn;                  // alias (xn dead after qkv GEMM)

  ln_naive<<<BL_, 64, 0, stream>>>(x, lng, lnb, xn);
  {
    int M = BL_, N = 128, K = D_;
    int grid = (M * N + 255) / 256;
    gemm_naive<1><<<grid, 256, 0, stream>>>(x, Wb1, nullptr, h1, nullptr, nullptr, M, N, K);
  }
  {
    int grid = (BL_ * H_ + 255) / 256;
    params_naive<<<grid, 256, 0, stream>>>(h1, Wb2, temp, gate, gpb, ceb, ldb);
  }
  {
    int M = BL_, N = 3 * D_, K = D_;
    int grid = (M * N + 255) / 256;
    gemm_naive<0><<<grid, 256, 0, stream>>>(xn, Wqkv, bqkv, qfb, kfb, vfb, M, N, K);
  }
  cld_naive<<<1, 64, 0, stream>>>(ldb, cldb);
  seq_ref<<<BH_, 64, 0, stream>>>(qfb, kfb, vfb, gpb, ceb, cldb, memg, memb, attn);
  {
    int M = BL_, N = D_, K = D_;
    int grid = (M * N + 255) / 256;
    gemm_naive<2><<<grid, 256, 0, stream>>>(attn, Wproj, bproj, out0, nullptr, nullptr, M, N, K);
  }
}

// Round 7
// 445.605 us; speedup vs baseline: 7.4314x; 7.4314x over previous
//
#include <hip/hip_runtime.h>
#include <math.h>

#define PI_F 3.14159265358979323846f

static constexpr int L_ = 512, D_ = 768, H_ = 12, DH_ = 64;
static constexpr int BL_ = 2048;            // B*L
static constexpr int BLD_ = BL_ * D_;       // 1572864
static constexpr int NC_ = 8;               // chunks (512/64)
static constexpr int BH_ = 48;              // B*H

__global__ void sentinel_kernel(float* out, float code, float aux) {
  out[0] = code; out[1] = aux;
}

// ---------------- LayerNorm over D=768 (fast) ----------------
__global__ __launch_bounds__(256) void ln_kernel(const float* __restrict__ x,
                                                 const float* __restrict__ g,
                                                 const float* __restrict__ b,
                                                 float* __restrict__ xn) {
  int row = blockIdx.x, tid = threadIdx.x;
  const float* xr = x + (size_t)row * D_;
  float v0 = xr[tid], v1 = xr[tid + 256], v2 = xr[tid + 512];
  float s = v0 + v1 + v2;
  float s2 = v0 * v0 + v1 * v1 + v2 * v2;
#pragma unroll
  for (int off = 32; off > 0; off >>= 1) { s += __shfl_xor(s, off); s2 += __shfl_xor(s2, off); }
  __shared__ float red[8];
  if ((tid & 63) == 0) { red[tid >> 6] = s; red[4 + (tid >> 6)] = s2; }
  __syncthreads();
  float st = red[0] + red[1] + red[2] + red[3];
  float qt = red[4] + red[5] + red[6] + red[7];
  float mu = st * (1.0f / D_);
  float var = qt * (1.0f / D_) - mu * mu;
  float rs = rsqrtf(var + 1e-5f);
  float* xo = xn + (size_t)row * D_;
  xo[tid]       = (v0 - mu) * rs * g[tid]       + b[tid];
  xo[tid + 256] = (v1 - mu) * rs * g[tid + 256] + b[tid + 256];
  xo[tid + 512] = (v2 - mu) * rs * g[tid + 512] + b[tid + 512];
}

// ---------------- fp32 tiled GEMM 64x64 (fast), epilogue by MODE ----------------
// MODE 0: qkv -> +bias, elu+1 on q,k; split O0/O1/O2 (stride 768)
// MODE 1: silu -> O0 (stride N)
// MODE 2: +bias -> O0 (stride N)
template <int MODE>
__global__ __launch_bounds__(256) void gemm_fast(const float* __restrict__ A,
                                                 const float* __restrict__ Bm,
                                                 const float* __restrict__ bias,
                                                 float* __restrict__ O0,
                                                 float* __restrict__ O1,
                                                 float* __restrict__ O2,
                                                 int N, int K) {
  __shared__ float As[16][68];
  __shared__ float Bs[16][68];
  int tid = threadIdx.x;
  int tx = tid & 15, ty = tid >> 4;
  int row0 = blockIdx.y * 64, col0 = blockIdx.x * 64;
  float acc[4][4] = {};
  int ar = tid >> 2, ak = (tid & 3) * 4;
  int bk = tid >> 4, bc = (tid & 15) * 4;
  for (int k0 = 0; k0 < K; k0 += 16) {
    float4 a4 = *(const float4*)&A[(size_t)(row0 + ar) * K + k0 + ak];
    As[ak + 0][ar] = a4.x; As[ak + 1][ar] = a4.y;
    As[ak + 2][ar] = a4.z; As[ak + 3][ar] = a4.w;
    *(float4*)&Bs[bk][bc] = *(const float4*)&Bm[(size_t)(k0 + bk) * N + col0 + bc];
    __syncthreads();
#pragma unroll
    for (int kk = 0; kk < 16; ++kk) {
      float4 av = *(float4*)&As[kk][ty * 4];
      float4 bv = *(float4*)&Bs[kk][tx * 4];
      acc[0][0] += av.x * bv.x; acc[0][1] += av.x * bv.y; acc[0][2] += av.x * bv.z; acc[0][3] += av.x * bv.w;
      acc[1][0] += av.y * bv.x; acc[1][1] += av.y * bv.y; acc[1][2] += av.y * bv.z; acc[1][3] += av.y * bv.w;
      acc[2][0] += av.z * bv.x; acc[2][1] += av.z * bv.y; acc[2][2] += av.z * bv.z; acc[2][3] += av.z * bv.w;
      acc[3][0] += av.w * bv.x; acc[3][1] += av.w * bv.y; acc[3][2] += av.w * bv.z; acc[3][3] += av.w * bv.w;
    }
    __syncthreads();
  }
  if (MODE == 0) {
    int sec = col0 / 768;
    float* O = (sec == 0) ? O0 : ((sec == 1) ? O1 : O2);
    int lc = col0 - sec * 768 + tx * 4;
    float b0 = bias[col0 + tx * 4 + 0], b1 = bias[col0 + tx * 4 + 1];
    float b2 = bias[col0 + tx * 4 + 2], b3 = bias[col0 + tx * 4 + 3];
#pragma unroll
    for (int ii = 0; ii < 4; ++ii) {
      int r = row0 + ty * 4 + ii;
      float4 v;
      v.x = acc[ii][0] + b0; v.y = acc[ii][1] + b1;
      v.z = acc[ii][2] + b2; v.w = acc[ii][3] + b3;
      if (sec < 2) {
        v.x = (v.x > 0.f) ? v.x + 1.f : expf(v.x);
        v.y = (v.y > 0.f) ? v.y + 1.f : expf(v.y);
        v.z = (v.z > 0.f) ? v.z + 1.f : expf(v.z);
        v.w = (v.w > 0.f) ? v.w + 1.f : expf(v.w);
      }
      *(float4*)&O[(size_t)r * 768 + lc] = v;
    }
  } else if (MODE == 1) {
#pragma unroll
    for (int ii = 0; ii < 4; ++ii) {
      int r = row0 + ty * 4 + ii;
      float4 v;
      v.x = acc[ii][0]; v.y = acc[ii][1]; v.z = acc[ii][2]; v.w = acc[ii][3];
      v.x = v.x / (1.f + expf(-v.x));
      v.y = v.y / (1.f + expf(-v.y));
      v.z = v.z / (1.f + expf(-v.z));
      v.w = v.w / (1.f + expf(-v.w));
      *(float4*)&O0[(size_t)r * N + col0 + tx * 4] = v;
    }
  } else {
    float b0 = bias[col0 + tx * 4 + 0], b1 = bias[col0 + tx * 4 + 1];
    float b2 = bias[col0 + tx * 4 + 2], b3 = bias[col0 + tx * 4 + 3];
#pragma unroll
    for (int ii = 0; ii < 4; ++ii) {
      int r = row0 + ty * 4 + ii;
      float4 v;
      v.x = acc[ii][0] + b0; v.y = acc[ii][1] + b1;
      v.z = acc[ii][2] + b2; v.w = acc[ii][3] + b3;
      *(float4*)&O0[(size_t)r * N + col0 + tx * 4] = v;
    }
  }
}

// ---------------- params (fast): h1 @ W_b2 -> gate / decay coefficients ----------------
__global__ __launch_bounds__(64) void params_kernel(const float* __restrict__ h1,
                                                    const float* __restrict__ Wb2,
                                                    const float* __restrict__ temp_p,
                                                    float* __restrict__ gate_out,
                                                    float* __restrict__ cg,
                                                    float* __restrict__ ce,
                                                    float* __restrict__ ld) {
  int t = blockIdx.x;
  int tid = threadIdx.x;
  __shared__ float hs[128];
  __shared__ float ps[60];
  *(float2*)&hs[tid * 2] = *(const float2*)&h1[(size_t)t * 128 + tid * 2];
  __syncthreads();
  if (tid < 60) {
    float acc = 0.f;
#pragma unroll 4
    for (int k = 0; k < 128; ++k) acc += hs[k] * Wb2[k * 60 + tid];
    ps[tid] = acc;
  }
  __syncthreads();
  if (tid < 12) {
    float p0 = ps[tid * 5 + 0], p1 = ps[tid * 5 + 1], p2 = ps[tid * 5 + 2];
    float p3 = ps[tid * 5 + 3], p4 = ps[tid * 5 + 4];
    float sa = 1.f / (1.f + expf(-p0));
    float sp = tanhf(p1) * PI_F;
    float ca = 1.f / (1.f + expf(-p2));
    float cp = tanhf(p3) * PI_F;
    float dec = 0.5f + 0.49f / (1.f + expf(-p4));
    float tmp = fminf(fmaxf(temp_p[0], 0.1f), 2.0f);
    float inter = tanhf(sa * ca * cosf(sp - cp)) * tmp;
    float gate = 1.f / (1.f + expf(-inter));
    gate_out[t * 12 + tid] = gate;
    int b = t >> 9, l = t & 511;
    int bhl = (b * 12 + tid) * L_ + l;
    float ema = 1.f - dec;
    cg[bhl] = ema * (1.f + gate);
    ce[bhl] = ema;
    ld[bhl] = logf(dec + 1e-8f);
  }
}

// ---------------- cumulative log-decay (fast) + chunk-end values ----------------
__global__ __launch_bounds__(64) void cld_kernel(const float* __restrict__ ld,
                                                 float* __restrict__ cld,
                                                 float* __restrict__ cEnd) {
  int bh = blockIdx.x;
  int lane = threadIdx.x;
  const float* src = ld + (size_t)bh * L_;
  float v[8];
  float s = 0.f;
#pragma unroll
  for (int i = 0; i < 8; ++i) { v[i] = src[lane * 8 + i]; s += v[i]; }
  float tot = s;
#pragma unroll
  for (int off = 1; off < 64; off <<= 1) {
    float n = __shfl_up(tot, off);
    if (lane >= off) tot += n;
  }
  float run = tot - s;
  float out7 = 0.f;
#pragma unroll
  for (int i = 0; i < 8; ++i) {
    run += v[i];
    float o = fmaxf(run, -85.f);
    cld[(size_t)bh * L_ + lane * 8 + i] = o;
    out7 = o;
  }
  if ((lane & 7) == 7) cEnd[bh * NC_ + (lane >> 3)] = out7;
}

// ---------------- overflow scan: exact fp32 mirror of ref's z cumsum ----------------
// Replicates r6's PASSING op order: s = ce*expf(-cld); cz += k*s. First token where
// any lane's cz hits +inf => all later dens are inf => output rows = mem_b.
__global__ __launch_bounds__(64) void infscan_kernel(const float* __restrict__ kf,
                                                     const float* __restrict__ ce,
                                                     const float* __restrict__ cld,
                                                     int* __restrict__ tstar) {
  int bh = blockIdx.x;
  int b = bh / H_, h = bh - b * H_;
  int e = threadIdx.x;
  float cz = 0.f;
  int tf = L_;
  for (int t = 0; t < L_; ++t) {
    int idx = bh * L_ + t;
    float s = ce[idx] * expf(-cld[idx]);
    float kv = kf[(size_t)(b * L_ + t) * D_ + h * DH_ + e];
    cz = cz + kv * s;
    if (tf == L_ && isinf(cz)) tf = t;
  }
#pragma unroll
  for (int off = 1; off < 64; off <<= 1) tf = min(tf, __shfl_xor(tf, off));
  if (e == 0) tstar[bh] = tf;
}

// ---------------- per-chunk summaries T_c (64x64) and z_c (64) ----------------
__global__ __launch_bounds__(256) void chunk_sum_kernel(const float* __restrict__ kf,
                                                        const float* __restrict__ vf,
                                                        const float* __restrict__ cg,
                                                        const float* __restrict__ ce,
                                                        const float* __restrict__ cld,
                                                        const float* __restrict__ cEnd,
                                                        float* __restrict__ T,
                                                        float* __restrict__ zc) {
  int blk = blockIdx.x;
  int c = blk & 7, bh = blk >> 3;
  int b = bh / H_, h = bh - b * H_;
  int tid = threadIdx.x;
  __shared__ float kfs[64][68];
  __shared__ float vfs[64][68];
  __shared__ float wv[64], wz[64];
  float cend = cEnd[blk];
  if (tid < 64) {
    int idx = bh * L_ + c * 64 + tid;
    float w = expf(cend - cld[idx]);
    wv[tid] = cg[idx] * w;
    wz[tid] = ce[idx] * w;
  }
  __syncthreads();
  int t = tid >> 2, g4 = (tid & 3) * 16;
  size_t rowb = (size_t)(b * L_ + c * 64 + t) * D_ + h * 64 + g4;
  float wvt = wv[t];
#pragma unroll
  for (int i = 0; i < 4; ++i) {
    *(float4*)&kfs[t][g4 + 4 * i] = *(const float4*)&kf[rowb + 4 * i];
    float4 vv = *(const float4*)&vf[rowb + 4 * i];
    vv.x *= wvt; vv.y *= wvt; vv.z *= wvt; vv.w *= wvt;
    *(float4*)&vfs[t][g4 + 4 * i] = vv;
  }
  __syncthreads();
  int d = tid >> 2, eb = (tid & 3) * 16;
  float4 a0 = {}, a1 = {}, a2 = {}, a3 = {};
  for (int tt = 0; tt < 64; ++tt) {
    float kd = kfs[tt][d];
    float4 x0 = *(float4*)&vfs[tt][eb + 0];
    float4 x1 = *(float4*)&vfs[tt][eb + 4];
    float4 x2 = *(float4*)&vfs[tt][eb + 8];
    float4 x3 = *(float4*)&vfs[tt][eb + 12];
    a0.x += kd * x0.x; a0.y += kd * x0.y; a0.z += kd * x0.z; a0.w += kd * x0.w;
    a1.x += kd * x1.x; a1.y += kd * x1.y; a1.z += kd * x1.z; a1.w += kd * x1.w;
    a2.x += kd * x2.x; a2.y += kd * x2.y; a2.z += kd * x2.z; a2.w += kd * x2.w;
    a3.x += kd * x3.x; a3.y += kd * x3.y; a3.z += kd * x3.z; a3.w += kd * x3.w;
  }
  size_t tb = (size_t)blk * 4096 + (size_t)d * 64 + eb;
  *(float4*)&T[tb + 0] = a0;
  *(float4*)&T[tb + 4] = a1;
  *(float4*)&T[tb + 8] = a2;
  *(float4*)&T[tb + 12] = a3;
  if (tid < 64) {
    float za = 0.f;
#pragma unroll 8
    for (int tt = 0; tt < 64; ++tt) za += kfs[tt][tid] * wz[tt];
    zc[blk * 64 + tid] = za;
  }
}

// ---------------- inter-chunk scan (IN-PLACE: Sprev aliases T) ----------------
__global__ __launch_bounds__(256) void scan_kernel(float* __restrict__ T,   // in: T_c, out: Sprev_c
                                                   const float* __restrict__ zc,
                                                   const float* __restrict__ cEnd,
                                                   float* __restrict__ zprev) {
  int bh = blockIdx.x, tid = threadIdx.x;
  float4 s0 = {}, s1 = {}, s2 = {}, s3 = {};
  float zs = 0.f;
  float prevEnd = 0.f;
  for (int c = 0; c < NC_; ++c) {
    int blk = bh * NC_ + c;
    float r = expf(cEnd[blk] - prevEnd);
    prevEnd = cEnd[blk];
    size_t base = (size_t)blk * 4096 + (size_t)tid * 16;
    float4 t0 = *(const float4*)&T[base + 0];   // load BEFORE overwrite (in-place)
    float4 t1 = *(const float4*)&T[base + 4];
    float4 t2 = *(const float4*)&T[base + 8];
    float4 t3 = *(const float4*)&T[base + 12];
    *(float4*)&T[base + 0] = s0;
    *(float4*)&T[base + 4] = s1;
    *(float4*)&T[base + 8] = s2;
    *(float4*)&T[base + 12] = s3;
    s0.x = s0.x * r + t0.x; s0.y = s0.y * r + t0.y; s0.z = s0.z * r + t0.z; s0.w = s0.w * r + t0.w;
    s1.x = s1.x * r + t1.x; s1.y = s1.y * r + t1.y; s1.z = s1.z * r + t1.z; s1.w = s1.w * r + t1.w;
    s2.x = s2.x * r + t2.x; s2.y = s2.y * r + t2.y; s2.z = s2.z * r + t2.z; s2.w = s2.w * r + t2.w;
    s3.x = s3.x * r + t3.x; s3.y = s3.y * r + t3.y; s3.z = s3.z * r + t3.z; s3.w = s3.w * r + t3.w;
    if (tid < 64) {
      zprev[blk * 64 + tid] = zs;
      zs = zs * r + zc[blk * 64 + tid];
    }
  }
}

// ---------------- per-chunk outputs (+ overflow mask), /den, LayerNorm(DH) ----------------
__global__ __launch_bounds__(256) void chunk_out_kernel(const float* __restrict__ qf,
                                                        const float* __restrict__ kf,
                                                        const float* __restrict__ vf,
                                                        const float* __restrict__ cg,
                                                        const float* __restrict__ ce,
                                                        const float* __restrict__ cld,
                                                        const float* __restrict__ cEnd,
                                                        const float* __restrict__ Sprev,
                                                        const float* __restrict__ zprev,
                                                        const int* __restrict__ tstar,
                                                        const float* __restrict__ mg,
                                                        const float* __restrict__ mb,
                                                        float* __restrict__ attn) {
  int blk = blockIdx.x;
  int c = blk & 7, bh = blk >> 3;
  int b = bh / H_, h = bh - b * H_;
  int tid = threadIdx.x;
  __shared__ float qfs[64][68];
  __shared__ float kfs[64][68];  // reused to hold M after score phase
  __shared__ float vfs[64][68];
  __shared__ float cldS[64], cgS[64], ceS[64], zS[64];
  int t = tid >> 2, g4 = (tid & 3) * 16;
  size_t rowb = (size_t)(b * L_ + c * 64 + t) * D_ + h * 64 + g4;
#pragma unroll
  for (int i = 0; i < 4; ++i) {
    *(float4*)&qfs[t][g4 + 4 * i] = *(const float4*)&qf[rowb + 4 * i];
    *(float4*)&kfs[t][g4 + 4 * i] = *(const float4*)&kf[rowb + 4 * i];
    *(float4*)&vfs[t][g4 + 4 * i] = *(const float4*)&vf[rowb + 4 * i];
  }
  if (tid < 64) {
    int idx = bh * L_ + c * 64 + tid;
    cldS[tid] = cld[idx];
    cgS[tid] = cg[idx];
    ceS[tid] = ce[idx];
    zS[tid] = zprev[blk * 64 + tid];
  }
  __syncthreads();
  float prevEnd = (c == 0) ? 0.f : cEnd[blk - 1];
  int ts = tstar[bh];
  int i = tid >> 2, jb = (tid & 3) * 16;
  float sc[16];
#pragma unroll
  for (int jj = 0; jj < 16; ++jj) sc[jj] = 0.f;
  for (int d = 0; d < 64; d += 4) {
    float4 q4 = *(float4*)&qfs[i][d];
#pragma unroll
    for (int jj = 0; jj < 16; ++jj) {
      float4 k4 = *(float4*)&kfs[jb + jj][d];
      sc[jj] += q4.x * k4.x + q4.y * k4.y + q4.z * k4.z + q4.w * k4.w;
    }
  }
  float cldi = cldS[i];
  float den = 0.f;
  float mvals[16];
#pragma unroll
  for (int jj = 0; jj < 16; ++jj) {
    int j = jb + jj;
    float w = (j <= i) ? expf(cldi - cldS[j]) : 0.f;
    float sw = sc[jj] * w;
    den += sw * ceS[j];
    mvals[jj] = sw * cgS[j];
  }
  float dz = 0.f;
#pragma unroll
  for (int dd = 0; dd < 16; ++dd) dz += qfs[i][jb + dd] * zS[jb + dd];
  den += __shfl_xor(den, 1); den += __shfl_xor(den, 2);
  dz += __shfl_xor(dz, 1);  dz += __shfl_xor(dz, 2);
  float wi = expf(cldi - prevEnd);
  den += wi * dz + 1e-6f;
  __syncthreads();
#pragma unroll
  for (int jj = 0; jj < 16; ++jj) kfs[i][jb + jj] = mvals[jj];
  __syncthreads();
  float4 o0 = {}, o1 = {}, o2 = {}, o3 = {};
  for (int j = 0; j < 64; ++j) {
    float m = kfs[i][j];
    float4 x0 = *(float4*)&vfs[j][jb + 0];
    float4 x1 = *(float4*)&vfs[j][jb + 4];
    float4 x2 = *(float4*)&vfs[j][jb + 8];
    float4 x3 = *(float4*)&vfs[j][jb + 12];
    o0.x += m * x0.x; o0.y += m * x0.y; o0.z += m * x0.z; o0.w += m * x0.w;
    o1.x += m * x1.x; o1.y += m * x1.y; o1.z += m * x1.z; o1.w += m * x1.w;
    o2.x += m * x2.x; o2.y += m * x2.y; o2.z += m * x2.z; o2.w += m * x2.w;
    o3.x += m * x3.x; o3.y += m * x3.y; o3.z += m * x3.z; o3.w += m * x3.w;
  }
  float4 p0 = {}, p1 = {}, p2 = {}, p3 = {};
  size_t sb = (size_t)blk * 4096;
  for (int d = 0; d < 64; ++d) {
    float qd = qfs[i][d];
    float4 x0 = *(const float4*)&Sprev[sb + d * 64 + jb + 0];
    float4 x1 = *(const float4*)&Sprev[sb + d * 64 + jb + 4];
    float4 x2 = *(const float4*)&Sprev[sb + d * 64 + jb + 8];
    float4 x3 = *(const float4*)&Sprev[sb + d * 64 + jb + 12];
    p0.x += qd * x0.x; p0.y += qd * x0.y; p0.z += qd * x0.z; p0.w += qd * x0.w;
    p1.x += qd * x1.x; p1.y += qd * x1.y; p1.z += qd * x1.z; p1.w += qd * x1.w;
    p2.x += qd * x2.x; p2.y += qd * x2.y; p2.z += qd * x2.z; p2.w += qd * x2.w;
    p3.x += qd * x3.x; p3.y += qd * x3.y; p3.z += qd * x3.z; p3.w += qd * x3.w;
  }
  size_t ob = (size_t)(b * L_ + c * 64 + i) * D_ + h * 64 + jb;
  if (c * 64 + i >= ts) {
    // ref: den=inf -> out=0 -> LN(0)=mem_b
#pragma unroll
    for (int q4i = 0; q4i < 4; ++q4i) {
      float4 w4;
      w4.x = mb[jb + q4i * 4 + 0]; w4.y = mb[jb + q4i * 4 + 1];
      w4.z = mb[jb + q4i * 4 + 2]; w4.w = mb[jb + q4i * 4 + 3];
      *(float4*)&attn[ob + q4i * 4] = w4;
    }
    return;
  }
  float inv = 1.0f / den;
  float o[16];
  o[0] = (o0.x + wi * p0.x) * inv;  o[1] = (o0.y + wi * p0.y) * inv;
  o[2] = (o0.z + wi * p0.z) * inv;  o[3] = (o0.w + wi * p0.w) * inv;
  o[4] = (o1.x + wi * p1.x) * inv;  o[5] = (o1.y + wi * p1.y) * inv;
  o[6] = (o1.z + wi * p1.z) * inv;  o[7] = (o1.w + wi * p1.w) * inv;
  o[8] = (o2.x + wi * p2.x) * inv;  o[9] = (o2.y + wi * p2.y) * inv;
  o[10] = (o2.z + wi * p2.z) * inv; o[11] = (o2.w + wi * p2.w) * inv;
  o[12] = (o3.x + wi * p3.x) * inv; o[13] = (o3.y + wi * p3.y) * inv;
  o[14] = (o3.z + wi * p3.z) * inv; o[15] = (o3.w + wi * p3.w) * inv;
  float s = 0.f, s2 = 0.f;
#pragma unroll
  for (int e2 = 0; e2 < 16; ++e2) { s += o[e2]; s2 += o[e2] * o[e2]; }
  s += __shfl_xor(s, 1);  s += __shfl_xor(s, 2);
  s2 += __shfl_xor(s2, 1); s2 += __shfl_xor(s2, 2);
  float mu = s * (1.f / 64.f);
  float var = s2 * (1.f / 64.f) - mu * mu;
  float rs = rsqrtf(var + 1e-5f);
#pragma unroll
  for (int q4i = 0; q4i < 4; ++q4i) {
    float4 w4;
    w4.x = (o[q4i * 4 + 0] - mu) * rs * mg[jb + q4i * 4 + 0] + mb[jb + q4i * 4 + 0];
    w4.y = (o[q4i * 4 + 1] - mu) * rs * mg[jb + q4i * 4 + 1] + mb[jb + q4i * 4 + 1];
    w4.z = (o[q4i * 4 + 2] - mu) * rs * mg[jb + q4i * 4 + 2] + mb[jb + q4i * 4 + 2];
    w4.w = (o[q4i * 4 + 3] - mu) * rs * mg[jb + q4i * 4 + 3] + mb[jb + q4i * 4 + 3];
    *(float4*)&attn[ob + q4i * 4] = w4;
  }
}

extern "C" void kernel_launch(void* const* d_in, const int* in_sizes, int n_in,
                              void* d_out, int out_size, void* d_ws, size_t ws_size,
                              hipStream_t stream) {
  const float* x     = (const float*)d_in[0];
  const float* Wqkv  = (const float*)d_in[1];
  const float* bqkv  = (const float*)d_in[2];
  const float* Wb1   = (const float*)d_in[3];
  const float* Wb2   = (const float*)d_in[4];
  const float* temp  = (const float*)d_in[5];
  const float* Wproj = (const float*)d_in[6];
  const float* bproj = (const float*)d_in[7];
  const float* lng   = (const float*)d_in[8];
  const float* lnb   = (const float*)d_in[9];
  const float* memg  = (const float*)d_in[10];
  const float* memb  = (const float*)d_in[11];
  float* out0 = (float*)d_out;    // fp32 output
  float* gate = out0 + BLD_;

  static const int expect[12] = {1572864, 1769472, 2304, 98304, 7680, 1,
                                 589824, 768, 768, 768, 64, 64};
  int bad = (n_in == 12) ? -1 : 99;
  if (bad < 0) for (int i = 0; i < 12; ++i) if (in_sizes[i] != expect[i]) { bad = i; break; }
  size_t need = (size_t)(4 * BLD_ + 262144 + 4 * 24576) * sizeof(float);  // 26.61 MB (proven available)
  if (bad >= 0) { sentinel_kernel<<<1, 1, 0, stream>>>(out0, 3.0e6f, (float)bad); return; }
  if (ws_size < need) { sentinel_kernel<<<1, 1, 0, stream>>>(out0, 1.0e6f, (float)(ws_size >> 20)); return; }

  float* ws   = (float*)d_ws;
  float* xn   = ws;                  // BLD_; dead after QKV GEMM -> reused as T/Sprev
  float* qfb  = xn + BLD_;           // BLD_; reused as attn by chunk_out (same rows)
  float* kfb  = qfb + BLD_;
  float* vfb  = kfb + BLD_;
  float* h1   = vfb + BLD_;          // 262144; dead after params -> zc/zprev/cEnd/tstar
  float* cgb  = h1 + 262144;
  float* ceb  = cgb + 24576;
  float* ldb  = ceb + 24576;
  float* cldb = ldb + 24576;
  float* Tb   = xn;                  // alias: T and (after in-place scan) Sprev
  float* zcb  = h1;                  // alias (h1 dead)
  float* zpv  = h1 + 24576;
  float* cEnd = h1 + 49152;          // 384
  int*   tstar = (int*)(h1 + 49536); // 48
  float* attn = qfb;                 // alias: chunk_out writes exactly the rows it read

  ln_kernel<<<BL_, 256, 0, stream>>>(x, lng, lnb, xn);
  gemm_fast<1><<<dim3(2, 32), 256, 0, stream>>>(x, Wb1, nullptr, h1, nullptr, nullptr, 128, 768);
  params_kernel<<<BL_, 64, 0, stream>>>(h1, Wb2, temp, gate, cgb, ceb, ldb);
  gemm_fast<0><<<dim3(36, 32), 256, 0, stream>>>(xn, Wqkv, bqkv, qfb, kfb, vfb, 2304, 768);
  cld_kernel<<<BH_, 64, 0, stream>>>(ldb, cldb, cEnd);
  infscan_kernel<<<BH_, 64, 0, stream>>>(kfb, ceb, cldb, tstar);
  chunk_sum_kernel<<<BH_ * NC_, 256, 0, stream>>>(kfb, vfb, cgb, ceb, cldb, cEnd, Tb, zcb);
  scan_kernel<<<BH_, 256, 0, stream>>>(Tb, zcb, cEnd, zpv);
  chunk_out_kernel<<<BH_ * NC_, 256, 0, stream>>>(qfb, kfb, vfb, cgb, ceb, cldb, cEnd,
                                                  Tb, zpv, tstar, memg, memb, attn);
  gemm_fast<2><<<dim3(12, 32), 256, 0, stream>>>(attn, Wproj, bproj, out0, nullptr, nullptr, 768, 768);
}